// Round 3
// baseline (266.706 us; speedup 1.0000x reference)
//
#include <hip/hip_runtime.h>

typedef unsigned short us;
typedef short bf16x8 __attribute__((ext_vector_type(8)));
typedef float f32x4 __attribute__((ext_vector_type(4)));
typedef float f32x16 __attribute__((ext_vector_type(16)));
typedef int i32x4 __attribute__((ext_vector_type(4)));

#define MFMA16(a, b, c) __builtin_amdgcn_mfma_f32_16x16x32_bf16(a, b, c, 0, 0, 0)
#define MFMA32(a, b, c) __builtin_amdgcn_mfma_f32_32x32x16_bf16(a, b, c, 0, 0, 0)

typedef const unsigned int __attribute__((address_space(1)))* gp_t;
typedef unsigned int __attribute__((address_space(3)))* lp_t;

__device__ __forceinline__ void gload16(const void* g, void* l) {
  __builtin_amdgcn_global_load_lds((gp_t)g, (lp_t)l, 16, 0, 0);
}

__device__ __forceinline__ us f2bf(float f) {
  unsigned u = __float_as_uint(f);
  u += 0x7fffu + ((u >> 16) & 1u);
  return (us)(u >> 16);
}

__device__ __forceinline__ unsigned cvtpk(float lo, float hi) {
  unsigned r;
  asm("v_cvt_pk_bf16_f32 %0, %1, %2" : "=v"(r) : "v"(lo), "v"(hi));
  return r;
}

// exchange lanes<32 / lanes>=32 halves of two words; both outputs usable (T12)
__device__ __forceinline__ void plswap(unsigned& a, unsigned& b) {
  auto r = __builtin_amdgcn_permlane32_swap(a, b, false, false);
  a = r[0];
  b = r[1];
}

// ---------------- convert fp32 -> bf16 (vectorized) ----------------
__global__ __launch_bounds__(256) void k_conv(const float* __restrict__ in,
                                              us* __restrict__ out, int n4) {
  int i = blockIdx.x * 256 + threadIdx.x;
  if (i >= n4) return;
  float4 f = reinterpret_cast<const float4*>(in)[i];
  ushort4 o;
  o.x = f2bf(f.x); o.y = f2bf(f.y); o.z = f2bf(f.z); o.w = f2bf(f.w);
  reinterpret_cast<ushort4*>(out)[i] = o;
}

// ---------------- transpose + convert W [K,N] f32 -> Wt [N,K] bf16 ----------------
__global__ __launch_bounds__(256) void k_transconv(const float* __restrict__ W,
                                                   us* __restrict__ Wt, int K, int N) {
  __shared__ float tile[32][33];
  int nbn = N >> 5;
  int kt = blockIdx.x / nbn, nt = blockIdx.x - kt * nbn;
  int tx = threadIdx.x & 31, ty = threadIdx.x >> 5;
#pragma unroll
  for (int j = 0; j < 4; ++j)
    tile[ty + 8 * j][tx] = W[(size_t)(kt * 32 + ty + 8 * j) * N + nt * 32 + tx];
  __syncthreads();
#pragma unroll
  for (int j = 0; j < 4; ++j)
    Wt[(size_t)(nt * 32 + ty + 8 * j) * K + kt * 32 + tx] = f2bf(tile[tx][ty + 8 * j]);
}

// ---------------- GEMM: A[M,K] bf16 x Bt[N,K] bf16 (m97 structure) ----------------
// EPI 0: q,k scatter [B,H,T,Dh] (+bias, q pre-scaled); v written TRANSPOSED
//        [B,H,Dh,T] with packed 8B stores. EPI 1: fp32 out (+bias).
template <int N, int EPI>
__global__ __launch_bounds__(256) void k_gemm(const us* __restrict__ A,
                                              const us* __restrict__ Bt,
                                              const float* __restrict__ bias,
                                              float* __restrict__ outf,
                                              us* __restrict__ qo, us* __restrict__ ko,
                                              us* __restrict__ vo) {
  constexpr int K = 1024;
  constexpr int NBN = N / 128;
  constexpr int NWG = 64 * NBN;  // M=8192
  constexpr float QSC = 0.125f * 1.44269504088896f;  // SCALE * log2(e) folded into q
  // bijective XCD swizzle (nwg % 8 == 0)
  int id = (blockIdx.x & 7) * (NWG / 8) + (blockIdx.x >> 3);
  int bm = id / NBN, bn = id % NBN;
  int lane = threadIdx.x & 63, wv = threadIdx.x >> 6;
  int wm = wv >> 1, wn = wv & 1;
  int c = lane & 15, g = lane >> 4;
  int r4 = lane >> 2, c4 = lane & 3;

  __shared__ __attribute__((aligned(16))) us As[128 * 32];
  __shared__ __attribute__((aligned(16))) us Bs[128 * 32];

  f32x4 acc[4][4] = {};

  const us* Abase = A + (size_t)(bm * 128) * K;
  const us* Bbase = Bt + (size_t)(bn * 128) * K;

  for (int k0 = 0; k0 < K; k0 += 32) {
#pragma unroll
    for (int t = 0; t < 2; ++t) {
      int inst = wv * 2 + t;
      gload16(Abase + (size_t)(inst * 16 + r4) * K + k0 + c4 * 8, As + inst * 512);
      gload16(Bbase + (size_t)(inst * 16 + r4) * K + k0 + c4 * 8, Bs + inst * 512);
    }
    __syncthreads();
    bf16x8 a[4], b[4];
#pragma unroll
    for (int m = 0; m < 4; ++m)
      a[m] = *reinterpret_cast<const bf16x8*>(&As[(wm * 64 + m * 16 + c) * 32 + g * 8]);
#pragma unroll
    for (int n = 0; n < 4; ++n)
      b[n] = *reinterpret_cast<const bf16x8*>(&Bs[(wn * 64 + n * 16 + c) * 32 + g * 8]);
#pragma unroll
    for (int m = 0; m < 4; ++m)
#pragma unroll
      for (int n = 0; n < 4; ++n) acc[m][n] = MFMA16(a[m], b[n], acc[m][n]);
    __syncthreads();
  }

#pragma unroll
  for (int m = 0; m < 4; ++m) {
#pragma unroll
    for (int n = 0; n < 4; ++n) {
      int gm0 = bm * 128 + wm * 64 + m * 16 + 4 * g;
      int gn = bn * 128 + wn * 64 + n * 16 + c;
      float bv = bias[gn];
      if (EPI == 0) {
        int which = gn >> 10, cc = gn & 1023;
        int hh = cc >> 6, dd = cc & 63;
        int b_ = gm0 >> 11, t0 = gm0 & 2047;
        if (which == 2) {
          ushort4 o;
          o.x = f2bf(acc[m][n][0] + bv);
          o.y = f2bf(acc[m][n][1] + bv);
          o.z = f2bf(acc[m][n][2] + bv);
          o.w = f2bf(acc[m][n][3] + bv);
          *reinterpret_cast<ushort4*>(
              &vo[(((size_t)b_ * 16 + hh) * 64 + dd) * 2048 + t0]) = o;
        } else {
          us* dst = which ? ko : qo;
          float sc = which ? 1.0f : QSC;
#pragma unroll
          for (int i = 0; i < 4; ++i)
            dst[(((size_t)b_ * 16 + hh) * 2048 + t0 + i) * 64 + dd] =
                f2bf((acc[m][n][i] + bv) * sc);
        }
      } else {
#pragma unroll
        for (int i = 0; i < 4; ++i) outf[(size_t)(gm0 + i) * N + gn] = acc[m][n][i] + bv;
      }
    }
  }
}

// ---------------- flash attention v3: swapped 32x32, 1 qslot per wave ----------------
// 1024 blocks x 4 waves = 4096 wave-tasks (64 bh x 64 qslots) -> 4 waves/SIMD.
// Longest-trip blocks dispatch first (qslot = 63 - (4p+wv)); bh pinned per XCD.
__global__ __launch_bounds__(256, 4) void k_attn2(const us* __restrict__ qg,
                                                  const us* __restrict__ kg,
                                                  const us* __restrict__ vT,
                                                  us* __restrict__ yb) {
  constexpr int T = 2048;
  int lane = threadIdx.x & 63;
  int wv = threadIdx.x >> 6;
  int b = blockIdx.x;            // 1024 blocks
  int x = b & 7, y = b >> 3;     // y in 0..127
  int bh = x * 8 + (y & 7);      // XCD x serves bh in [8x, 8x+8)
  int p = y >> 3;                // 0..15
  int b_ = bh >> 4, hh = bh & 15;
  int c = lane & 31, h = lane >> 5;

  const us* Qb = qg + (size_t)bh * T * 64;
  const us* Kb = kg + (size_t)bh * T * 64;
  const us* Vb = vT + (size_t)bh * 64 * T;

  int qslot = 63 - (4 * p + wv);  // big trips first in dispatch order
  int q0 = qslot * 32;
  int qrow = q0 + c;
  int trip = (qslot >> 1) + 1;

  bf16x8 qf[4];
#pragma unroll
  for (int ks = 0; ks < 4; ++ks)
    qf[ks] = *reinterpret_cast<const bf16x8*>(&Qb[(size_t)qrow * 64 + ks * 16 + h * 8]);

  f32x16 o0 = {}, o1 = {};
  float m = -1e30f, lsum = 0.f;

  for (int j = 0; j < trip; ++j) {
    int j0 = j * 64;
    // ---- QK^T swapped: S^T[k_local][q] ----
    f32x16 sA = {}, sB = {};
    __builtin_amdgcn_s_setprio(1);
#pragma unroll
    for (int ks = 0; ks < 4; ++ks) {
      bf16x8 kfA = *reinterpret_cast<const bf16x8*>(
          &Kb[(size_t)(j0 + c) * 64 + ks * 16 + h * 8]);
      bf16x8 kfB = *reinterpret_cast<const bf16x8*>(
          &Kb[(size_t)(j0 + 32 + c) * 64 + ks * 16 + h * 8]);
      sA = MFMA32(kfA, qf[ks], sA);
      sB = MFMA32(kfB, qf[ks], sB);
    }
    __builtin_amdgcn_s_setprio(0);
    // ---- causal mask (last tile only, contains the diagonal) ----
    if (j == trip - 1) {
#pragma unroll
      for (int r = 0; r < 16; ++r) {
        int kl = j0 + (r & 3) + 8 * (r >> 2) + 4 * h;
        if (kl > qrow) sA[r] = -1e30f;
        if (kl + 32 > qrow) sB[r] = -1e30f;
      }
    }
    // ---- online softmax: lane owns column q = q0+c ----
    float mx = -1e30f;
#pragma unroll
    for (int r = 0; r < 16; ++r) mx = fmaxf(mx, fmaxf(sA[r], sB[r]));
    mx = fmaxf(mx, __shfl_xor(mx, 32));
    if (!__all(mx <= m)) {  // defer-rescale (exact: skip when max unchanged)
      float mnew = fmaxf(m, mx);
      float alpha = __builtin_amdgcn_exp2f(m - mnew);
      m = mnew;
      lsum *= alpha;
#pragma unroll
      for (int r = 0; r < 16; ++r) { o0[r] *= alpha; o1[r] *= alpha; }
    }
    float rs = 0.f;
#pragma unroll
    for (int r = 0; r < 16; ++r) {
      sA[r] = __builtin_amdgcn_exp2f(sA[r] - m);
      sB[r] = __builtin_amdgcn_exp2f(sB[r] - m);
      rs += sA[r] + sB[r];
    }
    rs += __shfl_xor(rs, 32);
    lsum += rs;

    // ---- P -> bf16 B-fragments via cvt_pk + permlane32_swap; PV swapped ----
#pragma unroll
    for (int hb = 0; hb < 4; ++hb) {  // k-row blocks of 16: sA lo/hi, sB lo/hi
      int base = (hb & 1) * 8;
      unsigned w0, w1, w2, w3;
      if (hb < 2) {
        w0 = cvtpk(sA[base + 0], sA[base + 1]);
        w1 = cvtpk(sA[base + 2], sA[base + 3]);
        w2 = cvtpk(sA[base + 4], sA[base + 5]);
        w3 = cvtpk(sA[base + 6], sA[base + 7]);
      } else {
        w0 = cvtpk(sB[base + 0], sB[base + 1]);
        w1 = cvtpk(sB[base + 2], sB[base + 3]);
        w2 = cvtpk(sB[base + 4], sB[base + 5]);
        w3 = cvtpk(sB[base + 6], sB[base + 7]);
      }
      plswap(w0, w2);  // -> (pi0, pi2) for both halves
      plswap(w1, w3);  // -> (pi1, pi3)
      i32x4 pi;
      pi[0] = (int)w0; pi[1] = (int)w1; pi[2] = (int)w2; pi[3] = (int)w3;
      bf16x8 pa = __builtin_bit_cast(bf16x8, pi);
      int kb = j0 + hb * 16 + h * 8;
      bf16x8 vf0 = *reinterpret_cast<const bf16x8*>(&Vb[(size_t)c * T + kb]);
      bf16x8 vf1 = *reinterpret_cast<const bf16x8*>(&Vb[(size_t)(32 + c) * T + kb]);
      __builtin_amdgcn_s_setprio(1);
      o0 = MFMA32(vf0, pa, o0);  // O^T[d 0..31][q]
      o1 = MFMA32(vf1, pa, o1);  // O^T[d 32..63][q]
      __builtin_amdgcn_s_setprio(0);
    }
  }

  // ---- epilogue: lane holds q=q0+c col of O^T; d rows = crow(r,h) ----
  float inv = 1.0f / lsum;
  size_t ob = ((size_t)b_ * T + qrow) * 1024 + (size_t)hh * 64;
#pragma unroll
  for (int r = 0; r < 16; r += 2) {
    int d = (r & 3) + 8 * (r >> 2) + 4 * h;
    *reinterpret_cast<unsigned*>(&yb[ob + d]) = cvtpk(o0[r] * inv, o0[r + 1] * inv);
    *reinterpret_cast<unsigned*>(&yb[ob + 32 + d]) = cvtpk(o1[r] * inv, o1[r + 1] * inv);
  }
}

// ---------------- launcher ----------------
extern "C" void kernel_launch(void* const* d_in, const int* in_sizes, int n_in,
                              void* d_out, int out_size, void* d_ws, size_t ws_size,
                              hipStream_t stream) {
  (void)in_sizes; (void)n_in; (void)out_size; (void)ws_size;
  const float* x = (const float*)d_in[0];      // [4,2048,1024]
  const float* Wqkv = (const float*)d_in[1];   // [1024,3072]
  const float* bqkv = (const float*)d_in[2];   // [3072]
  const float* Wproj = (const float*)d_in[3];  // [1024,1024]
  const float* bproj = (const float*)d_in[4];  // [1024]
  float* out = (float*)d_out;                  // [4,2048,1024] f32

  char* ws = (char*)d_ws;
  us* xb = (us*)(ws);                    // 16 MB  [8192][1024]
  us* wqkvt = (us*)(ws + 16777216);      // 6 MB   [3072][1024]
  us* wprojt = (us*)(ws + 23068672);     // 2 MB   [1024][1024]
  us* qg = (us*)(ws + 25165824);         // 16 MB  [64][2048][64] (pre-scaled)
  us* kg = (us*)(ws + 41943040);         // 16 MB
  us* vT = (us*)(ws + 58720256);         // 16 MB  [64][64][2048] (written by GEMM)
  us* yb = (us*)(ws + 75497472);         // 16 MB  [8192][1024]

  k_conv<<<8192, 256, 0, stream>>>(x, xb, 2097152);
  k_transconv<<<3072, 256, 0, stream>>>(Wqkv, wqkvt, 1024, 3072);
  k_transconv<<<1024, 256, 0, stream>>>(Wproj, wprojt, 1024, 1024);
  k_gemm<3072, 0><<<64 * 24, 256, 0, stream>>>(xb, wqkvt, bqkv, nullptr, qg, kg, vT);
  k_attn2<<<1024, 256, 0, stream>>>(qg, kg, vT, yb);
  k_gemm<1024, 1><<<64 * 8, 256, 0, stream>>>(yb, wprojt, bproj, out, nullptr, nullptr, nullptr);
}

// Round 4
// 252.334 us; speedup vs baseline: 1.0570x; 1.0570x over previous
//
#include <hip/hip_runtime.h>

typedef unsigned short us;
typedef short bf16x8 __attribute__((ext_vector_type(8)));
typedef float f32x4 __attribute__((ext_vector_type(4)));
typedef float f32x16 __attribute__((ext_vector_type(16)));
typedef int i32x4 __attribute__((ext_vector_type(4)));

#define MFMA16(a, b, c) __builtin_amdgcn_mfma_f32_16x16x32_bf16(a, b, c, 0, 0, 0)
#define MFMA32(a, b, c) __builtin_amdgcn_mfma_f32_32x32x16_bf16(a, b, c, 0, 0, 0)

typedef const unsigned int __attribute__((address_space(1)))* gp_t;
typedef unsigned int __attribute__((address_space(3)))* lp_t;

__device__ __forceinline__ void gload16(const void* g, void* l) {
  __builtin_amdgcn_global_load_lds((gp_t)g, (lp_t)l, 16, 0, 0);
}

__device__ __forceinline__ us f2bf(float f) {
  unsigned u = __float_as_uint(f);
  u += 0x7fffu + ((u >> 16) & 1u);
  return (us)(u >> 16);
}

__device__ __forceinline__ unsigned cvtpk(float lo, float hi) {
  unsigned r;
  asm("v_cvt_pk_bf16_f32 %0, %1, %2" : "=v"(r) : "v"(lo), "v"(hi));
  return r;
}

// exchange lanes<32 / lanes>=32 halves of two words; both outputs usable (T12)
__device__ __forceinline__ void plswap(unsigned& a, unsigned& b) {
  auto r = __builtin_amdgcn_permlane32_swap(a, b, false, false);
  a = r[0];
  b = r[1];
}

// cross-half (lane^32) max/sum via permlane32_swap: pure VALU, no DS wait
__device__ __forceinline__ float xmax32(float x) {
  unsigned u = __float_as_uint(x);
  auto r = __builtin_amdgcn_permlane32_swap(u, u, false, false);
  return fmaxf(__uint_as_float(r[0]), __uint_as_float(r[1]));
}
__device__ __forceinline__ float xsum32(float x) {
  unsigned u = __float_as_uint(x);
  auto r = __builtin_amdgcn_permlane32_swap(u, u, false, false);
  return __uint_as_float(r[0]) + __uint_as_float(r[1]);
}

// ---------------- convert fp32 -> bf16 (vectorized) ----------------
__global__ __launch_bounds__(256) void k_conv(const float* __restrict__ in,
                                              us* __restrict__ out, int n4) {
  int i = blockIdx.x * 256 + threadIdx.x;
  if (i >= n4) return;
  float4 f = reinterpret_cast<const float4*>(in)[i];
  ushort4 o;
  o.x = f2bf(f.x); o.y = f2bf(f.y); o.z = f2bf(f.z); o.w = f2bf(f.w);
  reinterpret_cast<ushort4*>(out)[i] = o;
}

// ---------------- transpose + convert W [K,N] f32 -> Wt [N,K] bf16 ----------------
__global__ __launch_bounds__(256) void k_transconv(const float* __restrict__ W,
                                                   us* __restrict__ Wt, int K, int N) {
  __shared__ float tile[32][33];
  int nbn = N >> 5;
  int kt = blockIdx.x / nbn, nt = blockIdx.x - kt * nbn;
  int tx = threadIdx.x & 31, ty = threadIdx.x >> 5;
#pragma unroll
  for (int j = 0; j < 4; ++j)
    tile[ty + 8 * j][tx] = W[(size_t)(kt * 32 + ty + 8 * j) * N + nt * 32 + tx];
  __syncthreads();
#pragma unroll
  for (int j = 0; j < 4; ++j)
    Wt[(size_t)(nt * 32 + ty + 8 * j) * K + kt * 32 + tx] = f2bf(tile[tx][ty + 8 * j]);
}

// ---------------- GEMM: A[M,K] bf16 x Bt[N,K] bf16 (m97 structure) ----------------
// EPI 0: q,k scatter [B,H,T,Dh] (+bias, q pre-scaled); v written TRANSPOSED
//        [B,H,Dh,T] with packed 8B stores. EPI 1: fp32 out (+bias).
template <int N, int EPI>
__global__ __launch_bounds__(256) void k_gemm(const us* __restrict__ A,
                                              const us* __restrict__ Bt,
                                              const float* __restrict__ bias,
                                              float* __restrict__ outf,
                                              us* __restrict__ qo, us* __restrict__ ko,
                                              us* __restrict__ vo) {
  constexpr int K = 1024;
  constexpr int NBN = N / 128;
  constexpr int NWG = 64 * NBN;  // M=8192
  constexpr float QSC = 0.125f * 1.44269504088896f;  // SCALE * log2(e) folded into q
  // bijective XCD swizzle (nwg % 8 == 0)
  int id = (blockIdx.x & 7) * (NWG / 8) + (blockIdx.x >> 3);
  int bm = id / NBN, bn = id % NBN;
  int lane = threadIdx.x & 63, wv = threadIdx.x >> 6;
  int wm = wv >> 1, wn = wv & 1;
  int c = lane & 15, g = lane >> 4;
  int r4 = lane >> 2, c4 = lane & 3;

  __shared__ __attribute__((aligned(16))) us As[128 * 32];
  __shared__ __attribute__((aligned(16))) us Bs[128 * 32];

  f32x4 acc[4][4] = {};

  const us* Abase = A + (size_t)(bm * 128) * K;
  const us* Bbase = Bt + (size_t)(bn * 128) * K;

  for (int k0 = 0; k0 < K; k0 += 32) {
#pragma unroll
    for (int t = 0; t < 2; ++t) {
      int inst = wv * 2 + t;
      gload16(Abase + (size_t)(inst * 16 + r4) * K + k0 + c4 * 8, As + inst * 512);
      gload16(Bbase + (size_t)(inst * 16 + r4) * K + k0 + c4 * 8, Bs + inst * 512);
    }
    __syncthreads();
    bf16x8 a[4], b[4];
#pragma unroll
    for (int m = 0; m < 4; ++m)
      a[m] = *reinterpret_cast<const bf16x8*>(&As[(wm * 64 + m * 16 + c) * 32 + g * 8]);
#pragma unroll
    for (int n = 0; n < 4; ++n)
      b[n] = *reinterpret_cast<const bf16x8*>(&Bs[(wn * 64 + n * 16 + c) * 32 + g * 8]);
#pragma unroll
    for (int m = 0; m < 4; ++m)
#pragma unroll
      for (int n = 0; n < 4; ++n) acc[m][n] = MFMA16(a[m], b[n], acc[m][n]);
    __syncthreads();
  }

#pragma unroll
  for (int m = 0; m < 4; ++m) {
#pragma unroll
    for (int n = 0; n < 4; ++n) {
      int gm0 = bm * 128 + wm * 64 + m * 16 + 4 * g;
      int gn = bn * 128 + wn * 64 + n * 16 + c;
      float bv = bias[gn];
      if (EPI == 0) {
        int which = gn >> 10, cc = gn & 1023;
        int hh = cc >> 6, dd = cc & 63;
        int b_ = gm0 >> 11, t0 = gm0 & 2047;
        if (which == 2) {
          ushort4 o;
          o.x = f2bf(acc[m][n][0] + bv);
          o.y = f2bf(acc[m][n][1] + bv);
          o.z = f2bf(acc[m][n][2] + bv);
          o.w = f2bf(acc[m][n][3] + bv);
          *reinterpret_cast<ushort4*>(
              &vo[(((size_t)b_ * 16 + hh) * 64 + dd) * 2048 + t0]) = o;
        } else {
          us* dst = which ? ko : qo;
          float sc = which ? 1.0f : QSC;
#pragma unroll
          for (int i = 0; i < 4; ++i)
            dst[(((size_t)b_ * 16 + hh) * 2048 + t0 + i) * 64 + dd] =
                f2bf((acc[m][n][i] + bv) * sc);
        }
      } else {
#pragma unroll
        for (int i = 0; i < 4; ++i) outf[(size_t)(gm0 + i) * N + gn] = acc[m][n][i] + bv;
      }
    }
  }
}

// ---------------- flash attention v4: KV-split + in-block merge ----------------
// 2048 blocks (64 bh x 32 qslot-pairs), 4 waves each:
//   wv0: (A=63-p, KV lo half)  wv1: (A, KV hi half)
//   wv2: (B=p,    KV lo half)  wv3: (B, KV hi half)
// Every block = exactly 33 tiles total; longest wave <= 17 tiles; 8 blocks/CU
// queued -> hardware packs as blocks retire. Partials merged via LDS.
__global__ __launch_bounds__(256, 4) void k_attn2(const us* __restrict__ qg,
                                                  const us* __restrict__ kg,
                                                  const us* __restrict__ vT,
                                                  us* __restrict__ yb) {
  constexpr int T = 2048;
  int lane = threadIdx.x & 63;
  int wv = threadIdx.x >> 6;
  int b = blockIdx.x;            // 2048 blocks
  int x = b & 7, y = b >> 3;     // y in 0..255
  int bh = x * 8 + (y & 7);      // XCD x serves bh in [8x, 8x+8)
  int p = y >> 3;                // 0..31, ascending -> big qslots dispatch first
  int b_ = bh >> 4, hh = bh & 15;
  int c = lane & 31, h = lane >> 5;

  const us* Qb = qg + (size_t)bh * T * 64;
  const us* Kb = kg + (size_t)bh * T * 64;
  const us* Vb = vT + (size_t)bh * 64 * T;

  __shared__ float mrg[2][34][64];  // [qslot-in-block][o0(16)|o1(16)|m|l][lane]

  int qslot = (wv < 2) ? (63 - p) : p;
  int half = wv & 1;
  int q0 = qslot * 32;
  int qrow = q0 + c;
  int t = (qslot >> 1) + 1;      // total KV tiles for this qslot
  int jmid = (t + 1) >> 1;
  int jBeg = half ? jmid : 0;
  int jEnd = half ? t : jmid;

  bf16x8 qf[4];
#pragma unroll
  for (int ks = 0; ks < 4; ++ks)
    qf[ks] = *reinterpret_cast<const bf16x8*>(&Qb[(size_t)qrow * 64 + ks * 16 + h * 8]);

  f32x16 o0 = {}, o1 = {};
  float m = -1e30f, lsum = 0.f;

  for (int j = jBeg; j < jEnd; ++j) {
    int j0 = j * 64;
    // ---- QK^T swapped: S^T[k_local][q] ----
    f32x16 sA = {}, sB = {};
    __builtin_amdgcn_s_setprio(1);
#pragma unroll
    for (int ks = 0; ks < 4; ++ks) {
      bf16x8 kfA = *reinterpret_cast<const bf16x8*>(
          &Kb[(size_t)(j0 + c) * 64 + ks * 16 + h * 8]);
      bf16x8 kfB = *reinterpret_cast<const bf16x8*>(
          &Kb[(size_t)(j0 + 32 + c) * 64 + ks * 16 + h * 8]);
      sA = MFMA32(kfA, qf[ks], sA);
      sB = MFMA32(kfB, qf[ks], sB);
    }
    __builtin_amdgcn_s_setprio(0);
    // ---- causal mask (the tile containing the diagonal) ----
    if (j == t - 1) {
#pragma unroll
      for (int r = 0; r < 16; ++r) {
        int kl = j0 + (r & 3) + 8 * (r >> 2) + 4 * h;
        if (kl > qrow) sA[r] = -1e30f;
        if (kl + 32 > qrow) sB[r] = -1e30f;
      }
    }
    // ---- online softmax: lane owns column q = q0+c ----
    float mx = -1e30f;
#pragma unroll
    for (int r = 0; r < 16; ++r) mx = fmaxf(mx, fmaxf(sA[r], sB[r]));
    mx = xmax32(mx);
    if (!__all(mx <= m)) {  // defer-rescale (exact: skip when max unchanged)
      float mnew = fmaxf(m, mx);
      float alpha = __builtin_amdgcn_exp2f(m - mnew);
      m = mnew;
      lsum *= alpha;
#pragma unroll
      for (int r = 0; r < 16; ++r) { o0[r] *= alpha; o1[r] *= alpha; }
    }
    float rs = 0.f;
#pragma unroll
    for (int r = 0; r < 16; ++r) {
      sA[r] = __builtin_amdgcn_exp2f(sA[r] - m);
      sB[r] = __builtin_amdgcn_exp2f(sB[r] - m);
      rs += sA[r] + sB[r];
    }
    lsum += xsum32(rs);

    // ---- P -> bf16 B-fragments via cvt_pk + permlane32_swap; PV swapped ----
#pragma unroll
    for (int hb = 0; hb < 4; ++hb) {  // k-row blocks of 16: sA lo/hi, sB lo/hi
      int base = (hb & 1) * 8;
      unsigned w0, w1, w2, w3;
      if (hb < 2) {
        w0 = cvtpk(sA[base + 0], sA[base + 1]);
        w1 = cvtpk(sA[base + 2], sA[base + 3]);
        w2 = cvtpk(sA[base + 4], sA[base + 5]);
        w3 = cvtpk(sA[base + 6], sA[base + 7]);
      } else {
        w0 = cvtpk(sB[base + 0], sB[base + 1]);
        w1 = cvtpk(sB[base + 2], sB[base + 3]);
        w2 = cvtpk(sB[base + 4], sB[base + 5]);
        w3 = cvtpk(sB[base + 6], sB[base + 7]);
      }
      plswap(w0, w2);
      plswap(w1, w3);
      i32x4 pi;
      pi[0] = (int)w0; pi[1] = (int)w1; pi[2] = (int)w2; pi[3] = (int)w3;
      bf16x8 pa = __builtin_bit_cast(bf16x8, pi);
      int kb = j0 + hb * 16 + h * 8;
      bf16x8 vf0 = *reinterpret_cast<const bf16x8*>(&Vb[(size_t)c * T + kb]);
      bf16x8 vf1 = *reinterpret_cast<const bf16x8*>(&Vb[(size_t)(32 + c) * T + kb]);
      __builtin_amdgcn_s_setprio(1);
      o0 = MFMA32(vf0, pa, o0);  // O^T[d 0..31][q]
      o1 = MFMA32(vf1, pa, o1);  // O^T[d 32..63][q]
      __builtin_amdgcn_s_setprio(0);
    }
  }

  // ---- merge the two KV halves of each qslot ----
  if (half) {  // hi wave publishes partials
    int q2 = wv >> 1;
#pragma unroll
    for (int r = 0; r < 16; ++r) {
      mrg[q2][r][lane] = o0[r];
      mrg[q2][16 + r][lane] = o1[r];
    }
    mrg[q2][32][lane] = m;
    mrg[q2][33][lane] = lsum;
  }
  __syncthreads();
  if (half) return;

  int q2 = wv >> 1;
  float m1 = mrg[q2][32][lane], l1 = mrg[q2][33][lane];
  float M = fmaxf(m, m1);
  float a0 = __builtin_amdgcn_exp2f(m - M);
  float a1 = __builtin_amdgcn_exp2f(m1 - M);
  lsum = lsum * a0 + l1 * a1;
#pragma unroll
  for (int r = 0; r < 16; ++r) {
    o0[r] = o0[r] * a0 + mrg[q2][r][lane] * a1;
    o1[r] = o1[r] * a0 + mrg[q2][16 + r][lane] * a1;
  }

  // ---- epilogue: lane holds q=q0+c col of O^T; d rows = crow(r,h) ----
  float inv = 1.0f / lsum;
  size_t ob = ((size_t)b_ * T + qrow) * 1024 + (size_t)hh * 64;
#pragma unroll
  for (int r = 0; r < 16; r += 2) {
    int d = (r & 3) + 8 * (r >> 2) + 4 * h;
    *reinterpret_cast<unsigned*>(&yb[ob + d]) = cvtpk(o0[r] * inv, o0[r + 1] * inv);
    *reinterpret_cast<unsigned*>(&yb[ob + 32 + d]) = cvtpk(o1[r] * inv, o1[r + 1] * inv);
  }
}

// ---------------- launcher ----------------
extern "C" void kernel_launch(void* const* d_in, const int* in_sizes, int n_in,
                              void* d_out, int out_size, void* d_ws, size_t ws_size,
                              hipStream_t stream) {
  (void)in_sizes; (void)n_in; (void)out_size; (void)ws_size;
  const float* x = (const float*)d_in[0];      // [4,2048,1024]
  const float* Wqkv = (const float*)d_in[1];   // [1024,3072]
  const float* bqkv = (const float*)d_in[2];   // [3072]
  const float* Wproj = (const float*)d_in[3];  // [1024,1024]
  const float* bproj = (const float*)d_in[4];  // [1024]
  float* out = (float*)d_out;                  // [4,2048,1024] f32

  char* ws = (char*)d_ws;
  us* xb = (us*)(ws);                    // 16 MB  [8192][1024]
  us* wqkvt = (us*)(ws + 16777216);      // 6 MB   [3072][1024]
  us* wprojt = (us*)(ws + 23068672);     // 2 MB   [1024][1024]
  us* qg = (us*)(ws + 25165824);         // 16 MB  [64][2048][64] (pre-scaled)
  us* kg = (us*)(ws + 41943040);         // 16 MB
  us* vT = (us*)(ws + 58720256);         // 16 MB  [64][64][2048] (written by GEMM)
  us* yb = (us*)(ws + 75497472);         // 16 MB  [8192][1024]

  k_conv<<<8192, 256, 0, stream>>>(x, xb, 2097152);
  k_transconv<<<3072, 256, 0, stream>>>(Wqkv, wqkvt, 1024, 3072);
  k_transconv<<<1024, 256, 0, stream>>>(Wproj, wprojt, 1024, 1024);
  k_gemm<3072, 0><<<64 * 24, 256, 0, stream>>>(xb, wqkvt, bqkv, nullptr, qg, kg, vT);
  k_attn2<<<2048, 256, 0, stream>>>(qg, kg, vT, yb);
  k_gemm<1024, 1><<<64 * 8, 256, 0, stream>>>(yb, wprojt, bproj, out, nullptr, nullptr, nullptr);
}

// Round 5
// 201.802 us; speedup vs baseline: 1.3216x; 1.2504x over previous
//
#include <hip/hip_runtime.h>

typedef unsigned short us;
typedef short bf16x8 __attribute__((ext_vector_type(8)));
typedef float f32x4 __attribute__((ext_vector_type(4)));
typedef float f32x16 __attribute__((ext_vector_type(16)));
typedef int i32x4 __attribute__((ext_vector_type(4)));

#define MFMA16(a, b, c) __builtin_amdgcn_mfma_f32_16x16x32_bf16(a, b, c, 0, 0, 0)
#define MFMA32(a, b, c) __builtin_amdgcn_mfma_f32_32x32x16_bf16(a, b, c, 0, 0, 0)

typedef const unsigned int __attribute__((address_space(1)))* gp_t;
typedef unsigned int __attribute__((address_space(3)))* lp_t;

__device__ __forceinline__ void gload16(const void* g, void* l) {
  __builtin_amdgcn_global_load_lds((gp_t)g, (lp_t)l, 16, 0, 0);
}

__device__ __forceinline__ us f2bf(float f) {
  unsigned u = __float_as_uint(f);
  u += 0x7fffu + ((u >> 16) & 1u);
  return (us)(u >> 16);
}

__device__ __forceinline__ unsigned cvtpk(float lo, float hi) {
  unsigned r;
  asm("v_cvt_pk_bf16_f32 %0, %1, %2" : "=v"(r) : "v"(lo), "v"(hi));
  return r;
}

// exchange lanes<32 / lanes>=32 halves of two words; both outputs usable (T12)
__device__ __forceinline__ void plswap(unsigned& a, unsigned& b) {
  auto r = __builtin_amdgcn_permlane32_swap(a, b, false, false);
  a = r[0];
  b = r[1];
}

// cross-half (lane^32) max/sum via permlane32_swap: pure VALU, no DS wait
__device__ __forceinline__ float xmax32(float x) {
  unsigned u = __float_as_uint(x);
  auto r = __builtin_amdgcn_permlane32_swap(u, u, false, false);
  return fmaxf(__uint_as_float(r[0]), __uint_as_float(r[1]));
}
__device__ __forceinline__ float xsum32(float x) {
  unsigned u = __float_as_uint(x);
  auto r = __builtin_amdgcn_permlane32_swap(u, u, false, false);
  return __uint_as_float(r[0]) + __uint_as_float(r[1]);
}

// ---------------- convert fp32 -> bf16 (vectorized) ----------------
__global__ __launch_bounds__(256) void k_conv(const float* __restrict__ in,
                                              us* __restrict__ out, int n4) {
  int i = blockIdx.x * 256 + threadIdx.x;
  if (i >= n4) return;
  float4 f = reinterpret_cast<const float4*>(in)[i];
  ushort4 o;
  o.x = f2bf(f.x); o.y = f2bf(f.y); o.z = f2bf(f.z); o.w = f2bf(f.w);
  reinterpret_cast<ushort4*>(out)[i] = o;
}

// ---------------- transpose + convert W [K,N] f32 -> Wt [N,K] bf16 ----------------
__global__ __launch_bounds__(256) void k_transconv(const float* __restrict__ W,
                                                   us* __restrict__ Wt, int K, int N) {
  __shared__ float tile[32][33];
  int nbn = N >> 5;
  int kt = blockIdx.x / nbn, nt = blockIdx.x - kt * nbn;
  int tx = threadIdx.x & 31, ty = threadIdx.x >> 5;
#pragma unroll
  for (int j = 0; j < 4; ++j)
    tile[ty + 8 * j][tx] = W[(size_t)(kt * 32 + ty + 8 * j) * N + nt * 32 + tx];
  __syncthreads();
#pragma unroll
  for (int j = 0; j < 4; ++j)
    Wt[(size_t)(nt * 32 + ty + 8 * j) * K + kt * 32 + tx] = f2bf(tile[tx][ty + 8 * j]);
}

// ---------------- GEMM: A[M,K] bf16 x Bt[N,K] bf16 (m97 structure) ----------------
// EPI 0: q,k scatter [B,H,T,Dh] (+bias, q pre-scaled); v written TRANSPOSED
//        [B,H,Dh,T] with packed 8B stores. EPI 1: fp32 out (+bias).
template <int N, int EPI>
__global__ __launch_bounds__(256) void k_gemm(const us* __restrict__ A,
                                              const us* __restrict__ Bt,
                                              const float* __restrict__ bias,
                                              float* __restrict__ outf,
                                              us* __restrict__ qo, us* __restrict__ ko,
                                              us* __restrict__ vo) {
  constexpr int K = 1024;
  constexpr int NBN = N / 128;
  constexpr int NWG = 64 * NBN;  // M=8192
  constexpr float QSC = 0.125f * 1.44269504088896f;  // SCALE * log2(e) folded into q
  // bijective XCD swizzle (nwg % 8 == 0)
  int id = (blockIdx.x & 7) * (NWG / 8) + (blockIdx.x >> 3);
  int bm = id / NBN, bn = id % NBN;
  int lane = threadIdx.x & 63, wv = threadIdx.x >> 6;
  int wm = wv >> 1, wn = wv & 1;
  int c = lane & 15, g = lane >> 4;
  int r4 = lane >> 2, c4 = lane & 3;

  __shared__ __attribute__((aligned(16))) us As[128 * 32];
  __shared__ __attribute__((aligned(16))) us Bs[128 * 32];

  f32x4 acc[4][4] = {};

  const us* Abase = A + (size_t)(bm * 128) * K;
  const us* Bbase = Bt + (size_t)(bn * 128) * K;

  for (int k0 = 0; k0 < K; k0 += 32) {
#pragma unroll
    for (int t = 0; t < 2; ++t) {
      int inst = wv * 2 + t;
      gload16(Abase + (size_t)(inst * 16 + r4) * K + k0 + c4 * 8, As + inst * 512);
      gload16(Bbase + (size_t)(inst * 16 + r4) * K + k0 + c4 * 8, Bs + inst * 512);
    }
    __syncthreads();
    bf16x8 a[4], b[4];
#pragma unroll
    for (int m = 0; m < 4; ++m)
      a[m] = *reinterpret_cast<const bf16x8*>(&As[(wm * 64 + m * 16 + c) * 32 + g * 8]);
#pragma unroll
    for (int n = 0; n < 4; ++n)
      b[n] = *reinterpret_cast<const bf16x8*>(&Bs[(wn * 64 + n * 16 + c) * 32 + g * 8]);
#pragma unroll
    for (int m = 0; m < 4; ++m)
#pragma unroll
      for (int n = 0; n < 4; ++n) acc[m][n] = MFMA16(a[m], b[n], acc[m][n]);
    __syncthreads();
  }

#pragma unroll
  for (int m = 0; m < 4; ++m) {
#pragma unroll
    for (int n = 0; n < 4; ++n) {
      int gm0 = bm * 128 + wm * 64 + m * 16 + 4 * g;
      int gn = bn * 128 + wn * 64 + n * 16 + c;
      float bv = bias[gn];
      if (EPI == 0) {
        int which = gn >> 10, cc = gn & 1023;
        int hh = cc >> 6, dd = cc & 63;
        int b_ = gm0 >> 11, t0 = gm0 & 2047;
        if (which == 2) {
          ushort4 o;
          o.x = f2bf(acc[m][n][0] + bv);
          o.y = f2bf(acc[m][n][1] + bv);
          o.z = f2bf(acc[m][n][2] + bv);
          o.w = f2bf(acc[m][n][3] + bv);
          *reinterpret_cast<ushort4*>(
              &vo[(((size_t)b_ * 16 + hh) * 64 + dd) * 2048 + t0]) = o;
        } else {
          us* dst = which ? ko : qo;
          float sc = which ? 1.0f : QSC;
#pragma unroll
          for (int i = 0; i < 4; ++i)
            dst[(((size_t)b_ * 16 + hh) * 2048 + t0 + i) * 64 + dd] =
                f2bf((acc[m][n][i] + bv) * sc);
        }
      } else {
#pragma unroll
        for (int i = 0; i < 4; ++i) outf[(size_t)(gm0 + i) * N + gn] = acc[m][n][i] + bv;
      }
    }
  }
}

// ---------------- flash attention v5: LDS-staged KV shared by 4 waves ----------------
// Block = 128 q rows (4 waves x 32). 1024 blocks (64 bh x 16 qtiles), qtiles
// interleaved 15,0,14,1,... so any 4 consecutive blocks sum to ~68 tiles.
// K/V tiles staged once per block via global_load_lds (dbuf), read swizzled
// (rule #21: linear LDS dest + pre-swizzled source + same-XOR ds_read).
__global__ __launch_bounds__(256, 4) void k_attn3(const us* __restrict__ qg,
                                                  const us* __restrict__ kg,
                                                  const us* __restrict__ vT,
                                                  us* __restrict__ yb) {
  constexpr int T = 2048;
  __shared__ __attribute__((aligned(16))) us Ks[2][4096];  // [buf][64 rows][64 cols]
  __shared__ __attribute__((aligned(16))) us Vs[2][4096];  // [buf][64 d][64 t]
  int lane = threadIdx.x & 63;
  int wv = threadIdx.x >> 6;
  int b = blockIdx.x;            // 1024 blocks
  int x = b & 7, y = b >> 3;     // XCD x serves bh in [8x, 8x+8)
  int bh = x * 8 + (y & 7);
  int kk = y >> 3;               // 0..15
  int qt = (kk & 1) ? (kk >> 1) : (15 - (kk >> 1));  // 15,0,14,1,... balance mix
  int b_ = bh >> 4, hh = bh & 15;
  int c = lane & 31, h = lane >> 5;

  const us* Qb = qg + (size_t)bh * T * 64;
  const us* Kb = kg + (size_t)bh * T * 64;
  const us* Vb = vT + (size_t)bh * 64 * T;

  int nt = 2 * qt + 2;                // block KV-tile count
  int tw = 2 * qt + (wv >> 1) + 1;    // this wave's trip (wv0/1 skip last tile)
  int q0 = qt * 128 + wv * 32;
  int qrow = q0 + c;

  // stage source pre-swizzle: lane writes LDS linear (row=i*8+sl, colB=(lane&7)*16)
  // so it must FETCH logical col 8*((lane&7)^sl)  [sw(r)=((r&7)<<4), involution]
  int sl = lane >> 3;                  // row-in-group 0..7 (== r&7 at stage)
  int scol = 8 * ((lane & 7) ^ sl);    // source column, elements
  int swl = (c & 7) << 4;              // read-side XOR, bytes (rows c and c+32 share it)

  bf16x8 qf[4];
#pragma unroll
  for (int ks = 0; ks < 4; ++ks)
    qf[ks] = *reinterpret_cast<const bf16x8*>(&Qb[(size_t)qrow * 64 + ks * 16 + h * 8]);

  f32x16 o0 = {}, o1 = {};
  float m = -1e30f, lsum = 0.f;

  // prologue: stage tile 0 into buf 0 (each wave: K instrs wv,wv+4; V same)
#pragma unroll
  for (int t = 0; t < 2; ++t) {
    int i = wv + 4 * t;
    gload16(Kb + (size_t)(i * 8 + sl) * 64 + scol, &Ks[0][i * 512]);
    gload16(Vb + (size_t)(i * 8 + sl) * T + scol, &Vs[0][i * 512]);
  }

  for (int j = 0; j < nt; ++j) {
    int buf = j & 1;
    __syncthreads();  // drains own stage(j) vmcnt; all waves' stage(j) visible
    if (j + 1 < nt) {
      int j1 = (j + 1) * 64;
#pragma unroll
      for (int t = 0; t < 2; ++t) {
        int i = wv + 4 * t;
        gload16(Kb + (size_t)(j1 + i * 8 + sl) * 64 + scol, &Ks[buf ^ 1][i * 512]);
        gload16(Vb + (size_t)(i * 8 + sl) * T + j1 + scol, &Vs[buf ^ 1][i * 512]);
      }
    }
    if (j < tw) {
      int j0 = j * 64;
      const char* KsB = (const char*)Ks[buf];
      const char* VsB = (const char*)Vs[buf];
      // ---- QK^T swapped: S^T[k_local][q] ----
      f32x16 sA = {}, sB = {};
      __builtin_amdgcn_s_setprio(1);
#pragma unroll
      for (int ks = 0; ks < 4; ++ks) {
        int cb = (32 * ks + 16 * h) ^ swl;
        bf16x8 kfA = *reinterpret_cast<const bf16x8*>(KsB + c * 128 + cb);
        bf16x8 kfB = *reinterpret_cast<const bf16x8*>(KsB + (c + 32) * 128 + cb);
        sA = MFMA32(kfA, qf[ks], sA);
        sB = MFMA32(kfB, qf[ks], sB);
      }
      __builtin_amdgcn_s_setprio(0);
      // ---- causal mask (the tile containing this wave's diagonal) ----
      if (j == tw - 1) {
#pragma unroll
        for (int r = 0; r < 16; ++r) {
          int kl = j0 + (r & 3) + 8 * (r >> 2) + 4 * h;
          if (kl > qrow) sA[r] = -1e30f;
          if (kl + 32 > qrow) sB[r] = -1e30f;
        }
      }
      // ---- online softmax: lane owns column q = q0+c ----
      float mx = -1e30f;
#pragma unroll
      for (int r = 0; r < 16; ++r) mx = fmaxf(mx, fmaxf(sA[r], sB[r]));
      mx = xmax32(mx);
      if (!__all(mx <= m)) {  // defer-rescale (exact: skip when max unchanged)
        float mnew = fmaxf(m, mx);
        float alpha = __builtin_amdgcn_exp2f(m - mnew);
        m = mnew;
        lsum *= alpha;
#pragma unroll
        for (int r = 0; r < 16; ++r) { o0[r] *= alpha; o1[r] *= alpha; }
      }
      float rs = 0.f;
#pragma unroll
      for (int r = 0; r < 16; ++r) {
        sA[r] = __builtin_amdgcn_exp2f(sA[r] - m);
        sB[r] = __builtin_amdgcn_exp2f(sB[r] - m);
        rs += sA[r] + sB[r];
      }
      lsum += xsum32(rs);

      // ---- P -> bf16 B-fragments via cvt_pk + permlane32_swap; PV swapped ----
#pragma unroll
      for (int hb = 0; hb < 4; ++hb) {
        int base = (hb & 1) * 8;
        unsigned w0, w1, w2, w3;
        if (hb < 2) {
          w0 = cvtpk(sA[base + 0], sA[base + 1]);
          w1 = cvtpk(sA[base + 2], sA[base + 3]);
          w2 = cvtpk(sA[base + 4], sA[base + 5]);
          w3 = cvtpk(sA[base + 6], sA[base + 7]);
        } else {
          w0 = cvtpk(sB[base + 0], sB[base + 1]);
          w1 = cvtpk(sB[base + 2], sB[base + 3]);
          w2 = cvtpk(sB[base + 4], sB[base + 5]);
          w3 = cvtpk(sB[base + 6], sB[base + 7]);
        }
        plswap(w0, w2);
        plswap(w1, w3);
        i32x4 pi;
        pi[0] = (int)w0; pi[1] = (int)w1; pi[2] = (int)w2; pi[3] = (int)w3;
        bf16x8 pa = __builtin_bit_cast(bf16x8, pi);
        int cb = (32 * hb + 16 * h) ^ swl;
        bf16x8 vf0 = *reinterpret_cast<const bf16x8*>(VsB + c * 128 + cb);
        bf16x8 vf1 = *reinterpret_cast<const bf16x8*>(VsB + (c + 32) * 128 + cb);
        __builtin_amdgcn_s_setprio(1);
        o0 = MFMA32(vf0, pa, o0);  // O^T[d 0..31][q]
        o1 = MFMA32(vf1, pa, o1);  // O^T[d 32..63][q]
        __builtin_amdgcn_s_setprio(0);
      }
    }
  }

  // ---- epilogue: lane holds q=q0+c col of O^T; d rows = crow(r,h) ----
  float inv = 1.0f / lsum;
  size_t ob = ((size_t)b_ * T + qrow) * 1024 + (size_t)hh * 64;
#pragma unroll
  for (int r = 0; r < 16; r += 2) {
    int d = (r & 3) + 8 * (r >> 2) + 4 * h;
    *reinterpret_cast<unsigned*>(&yb[ob + d]) = cvtpk(o0[r] * inv, o0[r + 1] * inv);
    *reinterpret_cast<unsigned*>(&yb[ob + 32 + d]) = cvtpk(o1[r] * inv, o1[r + 1] * inv);
  }
}

// ---------------- launcher ----------------
extern "C" void kernel_launch(void* const* d_in, const int* in_sizes, int n_in,
                              void* d_out, int out_size, void* d_ws, size_t ws_size,
                              hipStream_t stream) {
  (void)in_sizes; (void)n_in; (void)out_size; (void)ws_size;
  const float* x = (const float*)d_in[0];      // [4,2048,1024]
  const float* Wqkv = (const float*)d_in[1];   // [1024,3072]
  const float* bqkv = (const float*)d_in[2];   // [3072]
  const float* Wproj = (const float*)d_in[3];  // [1024,1024]
  const float* bproj = (const float*)d_in[4];  // [1024]
  float* out = (float*)d_out;                  // [4,2048,1024] f32

  char* ws = (char*)d_ws;
  us* xb = (us*)(ws);                    // 16 MB  [8192][1024]
  us* wqkvt = (us*)(ws + 16777216);      // 6 MB   [3072][1024]
  us* wprojt = (us*)(ws + 23068672);     // 2 MB   [1024][1024]
  us* qg = (us*)(ws + 25165824);         // 16 MB  [64][2048][64] (pre-scaled)
  us* kg = (us*)(ws + 41943040);         // 16 MB
  us* vT = (us*)(ws + 58720256);         // 16 MB  [64][64][2048] (written by GEMM)
  us* yb = (us*)(ws + 75497472);         // 16 MB  [8192][1024]

  k_conv<<<8192, 256, 0, stream>>>(x, xb, 2097152);
  k_transconv<<<3072, 256, 0, stream>>>(Wqkv, wqkvt, 1024, 3072);
  k_transconv<<<1024, 256, 0, stream>>>(Wproj, wprojt, 1024, 1024);
  k_gemm<3072, 0><<<64 * 24, 256, 0, stream>>>(xb, wqkvt, bqkv, nullptr, qg, kg, vT);
  k_attn3<<<1024, 256, 0, stream>>>(qg, kg, vT, yb);
  k_gemm<1024, 1><<<64 * 8, 256, 0, stream>>>(yb, wprojt, bproj, out, nullptr, nullptr, nullptr);
}